// Round 15
// baseline (349.379 us; speedup 1.0000x reference)
//
#include <hip/hip_runtime.h>
#include <hip/hip_bf16.h>
#include <stdint.h>

typedef unsigned short u16;
typedef short s16x8 __attribute__((ext_vector_type(8)));
typedef u16 u16x8 __attribute__((ext_vector_type(8)));
typedef float f32x16 __attribute__((ext_vector_type(16)));

__device__ __forceinline__ u16 f2bf(float f) {
  union { float f; uint32_t u; } c; c.f = f;
  uint32_t u = c.u;
  u = u + 0x7fffu + ((u >> 16) & 1u);   // round-to-nearest-even
  return (u16)(u >> 16);
}
__device__ __forceinline__ float bf2f(u16 b) {
  union { uint32_t u; float f; } c; c.u = ((uint32_t)b) << 16;
  return c.f;
}

// async global->LDS, 16B per lane. LDS dest must be wave-uniform base + lane*16.
__device__ __forceinline__ void gld_lds16(const u16* g, u16* l) {
  __builtin_amdgcn_global_load_lds(
      (const __attribute__((address_space(1))) uint32_t*)g,
      (__attribute__((address_space(3))) uint32_t*)l,
      16, 0, 0);
}

// ---------------------------------------------------------------------------
// weight prep: z=0,1,2 -> Wq,Wk,Wv fp32 -> bf16 TRANSPOSED (64x64 LDS tiles);
//              z=3     -> Wo fp32 -> bf16 plain (flat copy)
// ---------------------------------------------------------------------------
__global__ __launch_bounds__(256) void cvt_wt(
    const float* __restrict__ Wq, const float* __restrict__ Wk,
    const float* __restrict__ Wv, const float* __restrict__ Wo,
    u16* __restrict__ WqT, u16* __restrict__ WkT, u16* __restrict__ WvT,
    u16* __restrict__ wo) {
  const int z = blockIdx.z;
  const int tid = threadIdx.x;
  if (z == 3) {
    const long base = ((long)(blockIdx.y * 16 + blockIdx.x)) * 4096 + tid * 16;
#pragma unroll
    for (int h = 0; h < 2; ++h) {
      const float4 a = *(const float4*)&Wo[base + h * 8];
      const float4 b = *(const float4*)&Wo[base + h * 8 + 4];
      u16x8 r;
      r[0] = f2bf(a.x); r[1] = f2bf(a.y); r[2] = f2bf(a.z); r[3] = f2bf(a.w);
      r[4] = f2bf(b.x); r[5] = f2bf(b.y); r[6] = f2bf(b.z); r[7] = f2bf(b.w);
      *(u16x8*)&wo[base + h * 8] = r;
    }
    return;
  }
  const float* src = (z == 0) ? Wq : (z == 1) ? Wk : Wv;
  u16* dst = (z == 0) ? WqT : (z == 1) ? WkT : WvT;
  __shared__ u16 t[64][66];
  const int r0 = blockIdx.x * 64, c0 = blockIdx.y * 64;
#pragma unroll
  for (int i = 0; i < 2; ++i) {
    const int ch = i * 256 + tid;
    const int r = ch >> 3, cc = ch & 7;
    const float4 a = *(const float4*)&src[(long)(r0 + r) * 1024 + c0 + cc * 8];
    const float4 b = *(const float4*)&src[(long)(r0 + r) * 1024 + c0 + cc * 8 + 4];
    t[r][cc * 8 + 0] = f2bf(a.x); t[r][cc * 8 + 1] = f2bf(a.y);
    t[r][cc * 8 + 2] = f2bf(a.z); t[r][cc * 8 + 3] = f2bf(a.w);
    t[r][cc * 8 + 4] = f2bf(b.x); t[r][cc * 8 + 5] = f2bf(b.y);
    t[r][cc * 8 + 6] = f2bf(b.z); t[r][cc * 8 + 7] = f2bf(b.w);
  }
  __syncthreads();
#pragma unroll
  for (int i = 0; i < 2; ++i) {
    const int ch = i * 256 + tid;
    const int c = ch >> 3, rr = ch & 7;
    u16x8 r8;
#pragma unroll
    for (int j = 0; j < 8; ++j) r8[j] = t[rr * 8 + j][c];
    *(u16x8*)&dst[(long)(c0 + c) * 1024 + r0 + rr * 8] = r8;
  }
}

// ---------------------------------------------------------------------------
// row softmax over 2048 cols, bf16 in/out (in place), fp32 math.
// S already has -1e30 at masked positions (mask fused into QK epilogue).
// ---------------------------------------------------------------------------
__global__ __launch_bounds__(256) void softmax_rows(u16* __restrict__ S) {
  const long base = (long)blockIdx.x * 2048;
  const int tid = threadIdx.x;
  const int lane = tid & 63, wave = tid >> 6;
  u16x8 raw = *(const u16x8*)&S[base + tid * 8];
  float v[8];
#pragma unroll
  for (int j = 0; j < 8; ++j) v[j] = bf2f(raw[j]);
  float m = v[0];
#pragma unroll
  for (int j = 1; j < 8; ++j) m = fmaxf(m, v[j]);
#pragma unroll
  for (int off = 32; off >= 1; off >>= 1) m = fmaxf(m, __shfl_xor(m, off));
  __shared__ float red[8];
  if (lane == 0) red[wave] = m;
  __syncthreads();
  m = fmaxf(fmaxf(red[0], red[1]), fmaxf(red[2], red[3]));
  float s = 0.f;
#pragma unroll
  for (int j = 0; j < 8; ++j) { v[j] = __expf(v[j] - m); s += v[j]; }
#pragma unroll
  for (int off = 32; off >= 1; off >>= 1) s += __shfl_xor(s, off);
  if (lane == 0) red[4 + wave] = s;
  __syncthreads();
  s = (red[4] + red[5]) + (red[6] + red[7]);
  const float inv = 1.f / s;
#pragma unroll
  for (int j = 0; j < 8; ++j) raw[j] = f2bf(v[j] * inv);
  *(u16x8*)&S[base + tid * 8] = raw;
}

// ---------------------------------------------------------------------------
// 128x128x64 GEMM (bt) body, m97/m103 TLP structure, now on
// mfma_f32_32x32x16_bf16 (17% fewer matrix-pipe cycles than 16x16x32; m119).
// Per wave 64x64 out = 2x2 tiles of 32x32, acc[2][2] f32x16.
// Input frag layout (extends verified 16x16x32 pattern + CDNA3 32x32x8):
//   A: row = lane&31, k = (lane>>5)*8 + j   (8 bf16, 4 VGPR)
//   B (from B^T rows): col = lane&31, same k
// C/D [m74/m101 verified]: col=lane&31, row=(reg&3)+8*(reg>>2)+4*(lane>>5).
// 256 thr = 4 waves (2x2), single-buffered 32 KiB LDS, 2 barriers/K-tile,
// 5 blocks/CU via LDS. T2 chunk-XOR swizzle, T1 XCD-bijective remap over
// caller-supplied logical grid, quarter-tile LDS epilogue (quarter h ->
// wm=h>>1, mi=h&1). MODE: 0 bf16 out; 1 f32 out. Optional fused mask.
// ---------------------------------------------------------------------------
union __align__(16) SmemT {
  u16 stage[2][128 * 64];        // 32 KiB: A-tile, B-tile
  float epi[32 * 132];           // 16.9 KiB epilogue C-staging (quarter-tile)
};

__device__ __forceinline__ s16x8 ldsfrag(const u16* p, int r, int c8) {
  return *(const s16x8*)&p[r * 64 + ((c8 ^ (r & 7)) << 3)];
}

__device__ __forceinline__ void stage128(const u16* __restrict__ gb, int row0,
                                         int K, int k0, u16* lbuf, int tid) {
#pragma unroll
  for (int i = 0; i < 4; ++i) {
    const int f = i * 256 + tid;
    const int rl = f >> 3, s = f & 7;
    const int gc = (s ^ (rl & 7)) << 3;     // pre-swizzled global col chunk
    gld_lds16(gb + (long)(row0 + rl) * K + k0 + gc, lbuf + f * 8);
  }
}

template<bool HAS_BIAS, int MODE, bool HAS_MASK>
__device__ __forceinline__ void gemm128_body(
    SmemT& sm, int tid, const u16* __restrict__ A, const u16* __restrict__ B,
    const float* __restrict__ bias, const int* __restrict__ mask,
    void* __restrict__ Cv, int M, int N, int K,
    long sA, long sB, long sC, long sMask, long sBias, float scale,
    int did, int nx, int ny, int nz) {
  // T1 swizzle over the logical (nx, ny, nz) grid; did in [0, nx*ny*nz)
  const int cpx = (nx * ny * nz) >> 3;                // grid %8 == 0
  const int nf = (did & 7) * cpx + (did >> 3);
  const int b = nf / (nx * ny);
  const int rr = nf % (nx * ny);
  const int bm = (rr / ny) * 128;
  const int bn = (rr % ny) * 128;

  const u16* Ab = A + (long)b * sA;
  const u16* Bb = B + (long)b * sB;
  const float* biasB = HAS_BIAS ? (bias + (long)b * sBias) : nullptr;
  const int lane = tid & 63, wave = tid >> 6;
  const int wm = wave >> 1, wn = wave & 1;            // 2x2 waves, 64x64 each
  const int l31 = lane & 31, l5 = lane >> 5;          // 32-lane row, k-half
  const int NT = K >> 6;

  f32x16 acc[2][2] = {};                              // [mi][ni] 32x32 tiles

  for (int t = 0; t < NT; ++t) {
    stage128(Ab, bm, K, t << 6, sm.stage[0], tid);
    stage128(Bb, bn, K, t << 6, sm.stage[1], tid);
    asm volatile("s_waitcnt vmcnt(0)" ::: "memory");
    __syncthreads();
#pragma unroll
    for (int ks = 0; ks < 4; ++ks) {                  // K = 4 x 16
      s16x8 af[2], bg[2];
#pragma unroll
      for (int mi = 0; mi < 2; ++mi)
        af[mi] = ldsfrag(sm.stage[0], wm * 64 + mi * 32 + l31, ks * 2 + l5);
#pragma unroll
      for (int ni = 0; ni < 2; ++ni)
        bg[ni] = ldsfrag(sm.stage[1], wn * 64 + ni * 32 + l31, ks * 2 + l5);
#pragma unroll
      for (int mi = 0; mi < 2; ++mi)
#pragma unroll
        for (int ni = 0; ni < 2; ++ni)
          acc[mi][ni] = __builtin_amdgcn_mfma_f32_32x32x16_bf16(
              af[mi], bg[ni], acc[mi][ni], 0, 0, 0);
    }
    __syncthreads();
  }

  // epilogue: quarter-tile (32 rows) LDS-staged, 4 passes.
  // quarter h covers block rows [h*32, h*32+32) = (wm = h>>1, mi = h&1).
  const long cb = (long)b * sC;
  const int q = tid & 7, r = tid >> 3;                // q:0..7, r:0..31
#pragma unroll
  for (int h = 0; h < 4; ++h) {
    __syncthreads();                                  // prior LDS use complete
    if (wm == (h >> 1)) {
      const int mi = h & 1;
#pragma unroll
      for (int ni = 0; ni < 2; ++ni) {
        const int c = wn * 64 + ni * 32 + l31;
        const float bvx = HAS_BIAS ? biasB[bn + c] : 0.f;
#pragma unroll
        for (int reg = 0; reg < 16; ++reg) {
          const int rl = (reg & 3) + 8 * (reg >> 2) + 4 * l5;   // 0..31
          sm.epi[rl * 132 + c] = acc[mi][ni][reg] * scale + bvx;
        }
      }
    }
    __syncthreads();
    const int growi = bm + h * 32 + r;
    const long grow = cb + (long)growi * N + bn;
    const long mrow = HAS_MASK
        ? ((long)b * sMask + (long)growi * (long)N + bn) : 0;
#pragma unroll
    for (int ch = 0; ch < 2; ++ch) {
      const int c0 = ch * 64 + q * 8;
      const float4 x = *(const float4*)&sm.epi[r * 132 + c0];
      const float4 y = *(const float4*)&sm.epi[r * 132 + c0 + 4];
      if (MODE == 1) {
        *(float4*)&((float*)Cv)[grow + c0] = x;
        *(float4*)&((float*)Cv)[grow + c0 + 4] = y;
      } else {
        u16x8 pk;
        if (HAS_MASK) {
          const int4 ma = *(const int4*)&mask[mrow + c0];
          const int4 mb = *(const int4*)&mask[mrow + c0 + 4];
          pk[0] = f2bf(ma.x ? x.x : -1e30f);
          pk[1] = f2bf(ma.y ? x.y : -1e30f);
          pk[2] = f2bf(ma.z ? x.z : -1e30f);
          pk[3] = f2bf(ma.w ? x.w : -1e30f);
          pk[4] = f2bf(mb.x ? y.x : -1e30f);
          pk[5] = f2bf(mb.y ? y.y : -1e30f);
          pk[6] = f2bf(mb.z ? y.z : -1e30f);
          pk[7] = f2bf(mb.w ? y.w : -1e30f);
        } else {
          pk[0] = f2bf(x.x); pk[1] = f2bf(x.y);
          pk[2] = f2bf(x.z); pk[3] = f2bf(x.w);
          pk[4] = f2bf(y.x); pk[5] = f2bf(y.y);
          pk[6] = f2bf(y.z); pk[7] = f2bf(y.w);
        }
        *(u16x8*)&((u16*)Cv)[grow + c0] = pk;
      }
    }
  }
}

// standalone GEMM kernel (QK with bias+mask; PV with f32 out)
template<bool HAS_BIAS, int MODE, bool HAS_MASK>
__global__ __launch_bounds__(256, 4) void gemm128(
    const u16* __restrict__ A, const u16* __restrict__ B,
    const float* __restrict__ bias, const int* __restrict__ mask,
    void* __restrict__ Cv,
    int M, int N, int K, long sA, long sB, long sC, long sMask, long sBias,
    float scale) {
  __shared__ SmemT sm;
  const int did = blockIdx.x + gridDim.x * (blockIdx.y + gridDim.y * blockIdx.z);
  gemm128_body<HAS_BIAS, MODE, HAS_MASK>(
      sm, threadIdx.x, A, B, bias, mask, Cv, M, N, K, sA, sB, sC, sMask,
      sBias, scale, did, gridDim.x, gridDim.y, gridDim.z);
}

// ---------------------------------------------------------------------------
// fused_prep (4352 blocks):
//  [0,4096):   input converts — blocks <2048 kv rows, else query rows
//  [4096,4224): merged weight GEMMs z=0: Mt=bt(WkT,WqT), z=1: Wvo=bt(wo,WvT)
//  [4224,4352): bgemv — <64: wvec = scale*WkT.bq ; >=64: bvo = wo.bv + bo
// ---------------------------------------------------------------------------
__global__ __launch_bounds__(256, 4) void fused_prep(
    const float* __restrict__ kv, const float* __restrict__ query,
    u16* __restrict__ kvbf, u16* __restrict__ qbf,
    const u16* __restrict__ WkT, const u16* __restrict__ WqT,
    u16* __restrict__ Mt, const u16* __restrict__ wo,
    const float* __restrict__ bq, const float* __restrict__ bv,
    const float* __restrict__ bo, float* __restrict__ wvec,
    float* __restrict__ bvo) {
  __shared__ SmemT sm;
  const int tid = threadIdx.x;
  const int bid = blockIdx.x;
  const int lane = tid & 63, wv_ = tid >> 6;
  if (bid < 4096) {
    const bool qside = bid >= 2048;
    const long blk = qside ? bid - 2048 : bid;
    const float* src_base = qside ? query : kv;
    u16* dst_base = qside ? qbf : kvbf;
#pragma unroll
    for (int r = 0; r < 2; ++r) {
      const long row = blk * 8 + wv_ * 2 + r;
      const float* src = &src_base[row * 1024 + lane * 16];
      const float4 a0 = *(const float4*)src;
      const float4 a1 = *(const float4*)(src + 4);
      const float4 a2 = *(const float4*)(src + 8);
      const float4 a3 = *(const float4*)(src + 12);
      u16x8 p0, p1;
      p0[0] = f2bf(a0.x); p0[1] = f2bf(a0.y); p0[2] = f2bf(a0.z); p0[3] = f2bf(a0.w);
      p0[4] = f2bf(a1.x); p0[5] = f2bf(a1.y); p0[6] = f2bf(a1.z); p0[7] = f2bf(a1.w);
      p1[0] = f2bf(a2.x); p1[1] = f2bf(a2.y); p1[2] = f2bf(a2.z); p1[3] = f2bf(a2.w);
      p1[4] = f2bf(a3.x); p1[5] = f2bf(a3.y); p1[6] = f2bf(a3.z); p1[7] = f2bf(a3.w);
      *(u16x8*)&dst_base[row * 1024 + lane * 16] = p0;
      *(u16x8*)&dst_base[row * 1024 + lane * 16 + 8] = p1;
    }
  } else if (bid < 4224) {
    gemm128_body<false, 0, false>(
        sm, tid, WkT, WqT, nullptr, nullptr, Mt, 1024, 1024, 1024,
        -2097152L, 2097152L, 1048576L, 0, 0, 1.f, bid - 4096, 8, 8, 2);
  } else {
    const int sub = bid - 4224;
    const bool second = sub >= 64;
    const u16* mat = second ? wo : WkT;
    const float* vec = second ? bv : bq;
    const int rb = (second ? sub - 64 : sub) * 16;
    float* w = sm.epi;
#pragma unroll
    for (int i = 0; i < 4; ++i) w[i * 256 + tid] = vec[i * 256 + tid];
    __syncthreads();
#pragma unroll
    for (int r = 0; r < 4; ++r) {
      const int row = rb + wv_ * 4 + r;
      const u16* p = &mat[(long)row * 1024 + lane * 16];
      const u16x8 a = *(const u16x8*)p;
      const u16x8 b = *(const u16x8*)(p + 8);
      float s = 0.f;
#pragma unroll
      for (int j = 0; j < 8; ++j) s += bf2f(a[j]) * w[lane * 16 + j];
#pragma unroll
      for (int j = 0; j < 8; ++j) s += bf2f(b[j]) * w[lane * 16 + 8 + j];
#pragma unroll
      for (int off = 32; off >= 1; off >>= 1) s += __shfl_xor(s, off);
      if (lane == 0) {
        if (second) bvo[row] = s + bo[row];
        else        wvec[row] = s * 0.03125f;
      }
    }
  }
}

// ---------------------------------------------------------------------------
// fused_mid (3072 blocks):
//  [0,1024):    qM  = bt(qbf, Mt)        (16384x1024x1024, grid 128x8x1)
//  [1024,2048): VwT = bt(Wvo, kv[b])     (1024x2048x1024 x8, grid 8x16x8)
//  [2048,3072): cgemv — cvec[row] = dot(kvbf[row,:], wvec)  (16 rows/block)
// ---------------------------------------------------------------------------
__global__ __launch_bounds__(256, 4) void fused_mid(
    const u16* __restrict__ qbf, const u16* __restrict__ Mt,
    u16* __restrict__ qM, const u16* __restrict__ Wvo,
    const u16* __restrict__ kvbf, u16* __restrict__ VwT,
    const float* __restrict__ wvec, float* __restrict__ cvec) {
  __shared__ SmemT sm;
  const int tid = threadIdx.x;
  const int bid = blockIdx.x;
  if (bid < 2048) {
    const bool isQM = bid < 1024;
    gemm128_body<false, 0, false>(
        sm, tid,
        isQM ? qbf : Wvo, isQM ? Mt : kvbf, nullptr, nullptr,
        isQM ? (void*)qM : (void*)VwT,
        isQM ? 16384 : 1024, isQM ? 1024 : 2048, 1024,
        0L, isQM ? 0L : 2097152L, isQM ? 0L : 2097152L, 0L, 0L, 1.f,
        isQM ? bid : bid - 1024,
        isQM ? 128 : 8, isQM ? 8 : 16, isQM ? 1 : 8);
  } else {
    const int lane = tid & 63, wv_ = tid >> 6;
    float* w = sm.epi;
#pragma unroll
    for (int i = 0; i < 4; ++i) w[i * 256 + tid] = wvec[i * 256 + tid];
    __syncthreads();
    const long rowbase = (long)(bid - 2048) * 16 + wv_ * 4;
#pragma unroll
    for (int r = 0; r < 4; ++r) {
      const long row = rowbase + r;
      const u16* p = &kvbf[row * 1024 + lane * 16];
      const u16x8 a = *(const u16x8*)p;
      const u16x8 b = *(const u16x8*)(p + 8);
      float s = 0.f;
#pragma unroll
      for (int j = 0; j < 8; ++j) s += bf2f(a[j]) * w[lane * 16 + j];
#pragma unroll
      for (int j = 0; j < 8; ++j) s += bf2f(b[j]) * w[lane * 16 + 8 + j];
#pragma unroll
      for (int off = 32; off >= 1; off >>= 1) s += __shfl_xor(s, off);
      if (lane == 0) cvec[row] = s;
    }
  }
}

// ---------------------------------------------------------------------------
// Algebraic fusions (torch Linear: x @ W.T + b; softmax over kv axis j):
//   S[q,j] = scale*(query.M)[q,:].kv[j,:] + c[j] (+ row-consts dropped),
//     M = Wq^T.Wk (as Mt = gemm_bt(WkT, WqT)), c[j] = scale*kv[j].(Wk^T bq)
//   out = P.Vw + bvo,  Vw^T = gemm_bt(Wvo, kv) (Wvo = Wo.Wv),
//   bvo = Wo.bv + bo   (valid since sum_j P = 1)
// ---------------------------------------------------------------------------
extern "C" void kernel_launch(void* const* d_in, const int* in_sizes, int n_in,
                              void* d_out, int out_size, void* d_ws, size_t ws_size,
                              hipStream_t stream) {
  const float* query = (const float*)d_in[0];   // [8,2048,1024]
  const float* kv    = (const float*)d_in[1];   // [8,2048,1024]
  const int*   mask  = (const int*)d_in[2];     // [8,2048,2048]
  const float* Wq = (const float*)d_in[3];
  const float* bq = (const float*)d_in[4];
  const float* Wk = (const float*)d_in[5];
  const float* bk = (const float*)d_in[6];      // unused: softmax-invariant
  const float* Wv = (const float*)d_in[7];
  const float* bv = (const float*)d_in[8];
  const float* Wo = (const float*)d_in[9];
  const float* bo = (const float*)d_in[10];
  float* out = (float*)d_out;
  (void)bk;

  char* ws = (char*)d_ws;
  const size_t MB = (size_t)1 << 20;
  u16* qbf  = (u16*)(ws + 0);          // 32MB query bf16
  u16* kvbf = (u16*)(ws + 32 * MB);    // 32MB kv bf16 (QK B-operand directly)
  u16* wo   = (u16*)(ws + 70 * MB);    // 2MB  Wo bf16 plain
  u16* WqT  = (u16*)(ws + 72 * MB);    // 2MB each: Wq^T, Wk^T, Wv^T
  u16* WkT  = (u16*)(ws + 74 * MB);
  u16* WvT  = (u16*)(ws + 76 * MB);
  u16* Mt   = (u16*)(ws + 78 * MB);    // 2MB  Mt = gemm_bt(WkT, WqT)
  u16* Wvo  = (u16*)(ws + 80 * MB);    // 2MB  Wo.Wv (Mt + 1048576 elems)
  float* wvec = (float*)(ws + 82 * MB);             // 4KB scale*Wk^T.bq
  float* bvo  = (float*)(ws + 82 * MB + 65536);     // 4KB Wo.bv+bo
  float* cvec = (float*)(ws + 83 * MB);             // 64KB c[8][2048]
  u16* qM   = (u16*)(ws + 84 * MB);    // 32MB query.M bf16
  u16* VwT  = (u16*)(ws + 116 * MB);   // 32MB [8][1024][2048]
  u16* S    = (u16*)(ws + 148 * MB);   // 64MB [8][2048][2048] bf16

  const long sQK = (long)2048 * 1024;
  const long sS  = (long)2048 * 2048;

  // 1) weight prep (transposed bf16 for Wq/Wk/Wv, plain for Wo)
  cvt_wt<<<dim3(16, 16, 4), 256, 0, stream>>>(Wq, Wk, Wv, Wo,
                                              WqT, WkT, WvT, wo);

  // 2) fused: input converts + merged weight GEMMs + bias GEMVs
  fused_prep<<<4352, 256, 0, stream>>>(kv, query, kvbf, qbf,
                                       WkT, WqT, Mt, wo, bq, bv, bo,
                                       wvec, bvo);

  // 3) fused: qM + VwT + cvec
  fused_mid<<<3072, 256, 0, stream>>>(qbf, Mt, qM, Wvo, kvbf, VwT,
                                      wvec, cvec);

  // 4) S = scale*(qM.kv^T) + c[b][j], masked (0 -> -1e30)
  gemm128<true, 0, true><<<dim3(16, 16, 8), 256, 0, stream>>>(
      qM, kvbf, cvec, mask, S, 2048, 2048, 1024, sQK, sQK, sS, sS, 2048,
      0.03125f);

  // 5) row softmax (in place on S)
  softmax_rows<<<16384, 256, 0, stream>>>(S);

  // 6) out = P.Vw + bvo   (fp32 direct to d_out, B = VwT)
  gemm128<true, 1, false><<<dim3(16, 8, 8), 256, 0, stream>>>(
      S, VwT, bvo, nullptr, out, 2048, 1024, 2048, sS, sQK, sQK, 0, 0, 1.f);
}

// Round 16
// 316.495 us; speedup vs baseline: 1.1039x; 1.1039x over previous
//
#include <hip/hip_runtime.h>
#include <hip/hip_bf16.h>
#include <stdint.h>

typedef unsigned short u16;
typedef short s16x8 __attribute__((ext_vector_type(8)));
typedef u16 u16x8 __attribute__((ext_vector_type(8)));
typedef float f32x4 __attribute__((ext_vector_type(4)));

__device__ __forceinline__ u16 f2bf(float f) {
  union { float f; uint32_t u; } c; c.f = f;
  uint32_t u = c.u;
  u = u + 0x7fffu + ((u >> 16) & 1u);   // round-to-nearest-even
  return (u16)(u >> 16);
}
__device__ __forceinline__ float bf2f(u16 b) {
  union { uint32_t u; float f; } c; c.u = ((uint32_t)b) << 16;
  return c.f;
}

// async global->LDS, 16B per lane. LDS dest must be wave-uniform base + lane*16.
__device__ __forceinline__ void gld_lds16(const u16* g, u16* l) {
  __builtin_amdgcn_global_load_lds(
      (const __attribute__((address_space(1))) uint32_t*)g,
      (__attribute__((address_space(3))) uint32_t*)l,
      16, 0, 0);
}

// ---------------------------------------------------------------------------
// weight prep: z=0,1,2 -> Wq,Wk,Wv fp32 -> bf16 TRANSPOSED (64x64 LDS tiles);
//              z=3     -> Wo fp32 -> bf16 plain (flat copy)
// ---------------------------------------------------------------------------
__global__ __launch_bounds__(256) void cvt_wt(
    const float* __restrict__ Wq, const float* __restrict__ Wk,
    const float* __restrict__ Wv, const float* __restrict__ Wo,
    u16* __restrict__ WqT, u16* __restrict__ WkT, u16* __restrict__ WvT,
    u16* __restrict__ wo) {
  const int z = blockIdx.z;
  const int tid = threadIdx.x;
  if (z == 3) {
    const long base = ((long)(blockIdx.y * 16 + blockIdx.x)) * 4096 + tid * 16;
#pragma unroll
    for (int h = 0; h < 2; ++h) {
      const float4 a = *(const float4*)&Wo[base + h * 8];
      const float4 b = *(const float4*)&Wo[base + h * 8 + 4];
      u16x8 r;
      r[0] = f2bf(a.x); r[1] = f2bf(a.y); r[2] = f2bf(a.z); r[3] = f2bf(a.w);
      r[4] = f2bf(b.x); r[5] = f2bf(b.y); r[6] = f2bf(b.z); r[7] = f2bf(b.w);
      *(u16x8*)&wo[base + h * 8] = r;
    }
    return;
  }
  const float* src = (z == 0) ? Wq : (z == 1) ? Wk : Wv;
  u16* dst = (z == 0) ? WqT : (z == 1) ? WkT : WvT;
  __shared__ u16 t[64][66];
  const int r0 = blockIdx.x * 64, c0 = blockIdx.y * 64;
#pragma unroll
  for (int i = 0; i < 2; ++i) {
    const int ch = i * 256 + tid;
    const int r = ch >> 3, cc = ch & 7;
    const float4 a = *(const float4*)&src[(long)(r0 + r) * 1024 + c0 + cc * 8];
    const float4 b = *(const float4*)&src[(long)(r0 + r) * 1024 + c0 + cc * 8 + 4];
    t[r][cc * 8 + 0] = f2bf(a.x); t[r][cc * 8 + 1] = f2bf(a.y);
    t[r][cc * 8 + 2] = f2bf(a.z); t[r][cc * 8 + 3] = f2bf(a.w);
    t[r][cc * 8 + 4] = f2bf(b.x); t[r][cc * 8 + 5] = f2bf(b.y);
    t[r][cc * 8 + 6] = f2bf(b.z); t[r][cc * 8 + 7] = f2bf(b.w);
  }
  __syncthreads();
#pragma unroll
  for (int i = 0; i < 2; ++i) {
    const int ch = i * 256 + tid;
    const int c = ch >> 3, rr = ch & 7;
    u16x8 r8;
#pragma unroll
    for (int j = 0; j < 8; ++j) r8[j] = t[rr * 8 + j][c];
    *(u16x8*)&dst[(long)(c0 + c) * 1024 + r0 + rr * 8] = r8;
  }
}

// ---------------------------------------------------------------------------
// row softmax over 2048 cols, bf16 in/out (in place), fp32 math.
// S already has -1e30 at masked positions (mask fused into QK epilogue).
// ---------------------------------------------------------------------------
__global__ __launch_bounds__(256) void softmax_rows(u16* __restrict__ S) {
  const long base = (long)blockIdx.x * 2048;
  const int tid = threadIdx.x;
  const int lane = tid & 63, wave = tid >> 6;
  u16x8 raw = *(const u16x8*)&S[base + tid * 8];
  float v[8];
#pragma unroll
  for (int j = 0; j < 8; ++j) v[j] = bf2f(raw[j]);
  float m = v[0];
#pragma unroll
  for (int j = 1; j < 8; ++j) m = fmaxf(m, v[j]);
#pragma unroll
  for (int off = 32; off >= 1; off >>= 1) m = fmaxf(m, __shfl_xor(m, off));
  __shared__ float red[8];
  if (lane == 0) red[wave] = m;
  __syncthreads();
  m = fmaxf(fmaxf(red[0], red[1]), fmaxf(red[2], red[3]));
  float s = 0.f;
#pragma unroll
  for (int j = 0; j < 8; ++j) { v[j] = __expf(v[j] - m); s += v[j]; }
#pragma unroll
  for (int off = 32; off >= 1; off >>= 1) s += __shfl_xor(s, off);
  if (lane == 0) red[4 + wave] = s;
  __syncthreads();
  s = (red[4] + red[5]) + (red[6] + red[7]);
  const float inv = 1.f / s;
#pragma unroll
  for (int j = 0; j < 8; ++j) raw[j] = f2bf(v[j] * inv);
  *(u16x8*)&S[base + tid * 8] = raw;
}

// ---------------------------------------------------------------------------
// 128x128x64 GEMM (bt) body, m97/m103 TLP structure (~890 TF verified):
// 256 thr = 4 waves (2x2), single-buffered 32 KiB LDS, 2 barriers/K-tile,
// 5 blocks/CU via LDS. T2 chunk-XOR swizzle, T1 XCD-bijective remap over
// the caller-supplied logical grid (did, nx, ny, nz), quarter-tile LDS
// epilogue. MODE: 0 bf16 out; 1 f32 out. Optional fused mask (0 -> -1e30).
// Batched via sA/sB/sC (negative strides legal).
// NOTE (r15): 16x16x32 MFMA is the right shape here — 32x32x16 has only
// 2 distinct k-chunk columns per wave -> 4-way slot aliasing in the XOR
// swizzle (bank conflicts x17, +13% time). Verified, do not re-try.
// ---------------------------------------------------------------------------
union __align__(16) SmemT {
  u16 stage[2][128 * 64];        // 32 KiB: A-tile, B-tile
  float epi[32 * 132];           // 16.9 KiB epilogue C-staging (quarter-tile)
};

__device__ __forceinline__ s16x8 ldsfrag(const u16* p, int r, int c8) {
  return *(const s16x8*)&p[r * 64 + ((c8 ^ (r & 7)) << 3)];
}

__device__ __forceinline__ void stage128(const u16* __restrict__ gb, int row0,
                                         int K, int k0, u16* lbuf, int tid) {
#pragma unroll
  for (int i = 0; i < 4; ++i) {
    const int f = i * 256 + tid;
    const int rl = f >> 3, s = f & 7;
    const int gc = (s ^ (rl & 7)) << 3;     // pre-swizzled global col chunk
    gld_lds16(gb + (long)(row0 + rl) * K + k0 + gc, lbuf + f * 8);
  }
}

template<bool HAS_BIAS, int MODE, bool HAS_MASK>
__device__ __forceinline__ void gemm128_body(
    SmemT& sm, int tid, const u16* __restrict__ A, const u16* __restrict__ B,
    const float* __restrict__ bias, const int* __restrict__ mask,
    void* __restrict__ Cv, int M, int N, int K,
    long sA, long sB, long sC, long sMask, long sBias, float scale,
    int did, int nx, int ny, int nz) {
  // T1 swizzle over the logical (nx, ny, nz) grid; did in [0, nx*ny*nz)
  const int cpx = (nx * ny * nz) >> 3;                // grid %8 == 0
  const int nf = (did & 7) * cpx + (did >> 3);
  const int b = nf / (nx * ny);
  const int rr = nf % (nx * ny);
  const int bm = (rr / ny) * 128;
  const int bn = (rr % ny) * 128;

  const u16* Ab = A + (long)b * sA;
  const u16* Bb = B + (long)b * sB;
  const float* biasB = HAS_BIAS ? (bias + (long)b * sBias) : nullptr;
  const int lane = tid & 63, wave = tid >> 6;
  const int wm = wave >> 1, wn = wave & 1;            // 2x2 waves, 64x64 each
  const int lr = lane & 15, lk = lane >> 4;
  const int NT = K >> 6;

  f32x4 acc[4][4] = {};

  for (int t = 0; t < NT; ++t) {
    stage128(Ab, bm, K, t << 6, sm.stage[0], tid);
    stage128(Bb, bn, K, t << 6, sm.stage[1], tid);
    asm volatile("s_waitcnt vmcnt(0)" ::: "memory");
    __syncthreads();
#pragma unroll
    for (int ks = 0; ks < 2; ++ks) {
      s16x8 af[4], bg[4];
#pragma unroll
      for (int mi = 0; mi < 4; ++mi)
        af[mi] = ldsfrag(sm.stage[0], wm * 64 + mi * 16 + lr, ks * 4 + lk);
#pragma unroll
      for (int ni = 0; ni < 4; ++ni)
        bg[ni] = ldsfrag(sm.stage[1], wn * 64 + ni * 16 + lr, ks * 4 + lk);
#pragma unroll
      for (int mi = 0; mi < 4; ++mi)
#pragma unroll
        for (int ni = 0; ni < 4; ++ni)
          acc[mi][ni] = __builtin_amdgcn_mfma_f32_16x16x32_bf16(
              af[mi], bg[ni], acc[mi][ni], 0, 0, 0);
    }
    __syncthreads();
  }

  // epilogue: quarter-tile (32 rows) LDS-staged, 4 passes
  const long cb = (long)b * sC;
  const int q = tid & 7, r = tid >> 3;                // q:0..7, r:0..31
#pragma unroll
  for (int h = 0; h < 4; ++h) {
    __syncthreads();                                  // prior LDS use complete
    if (wm == (h >> 1)) {
      const int mi0 = (h & 1) * 2;
#pragma unroll
      for (int mm = 0; mm < 2; ++mm) {
        const int mi = mi0 + mm;
#pragma unroll
        for (int ni = 0; ni < 4; ++ni) {
          const int c = wn * 64 + ni * 16 + lr;
          const float bvx = HAS_BIAS ? biasB[bn + c] : 0.f;
#pragma unroll
          for (int j = 0; j < 4; ++j)
            sm.epi[(mm * 16 + (lk << 2) + j) * 132 + c] =
                acc[mi][ni][j] * scale + bvx;
        }
      }
    }
    __syncthreads();
    const int growi = bm + h * 32 + r;
    const long grow = cb + (long)growi * N + bn;
    const long mrow = HAS_MASK
        ? ((long)b * sMask + (long)growi * (long)N + bn) : 0;
#pragma unroll
    for (int ch = 0; ch < 2; ++ch) {
      const int c0 = ch * 64 + q * 8;
      const float4 x = *(const float4*)&sm.epi[r * 132 + c0];
      const float4 y = *(const float4*)&sm.epi[r * 132 + c0 + 4];
      if (MODE == 1) {
        *(float4*)&((float*)Cv)[grow + c0] = x;
        *(float4*)&((float*)Cv)[grow + c0 + 4] = y;
      } else {
        u16x8 pk;
        if (HAS_MASK) {
          const int4 ma = *(const int4*)&mask[mrow + c0];
          const int4 mb = *(const int4*)&mask[mrow + c0 + 4];
          pk[0] = f2bf(ma.x ? x.x : -1e30f);
          pk[1] = f2bf(ma.y ? x.y : -1e30f);
          pk[2] = f2bf(ma.z ? x.z : -1e30f);
          pk[3] = f2bf(ma.w ? x.w : -1e30f);
          pk[4] = f2bf(mb.x ? y.x : -1e30f);
          pk[5] = f2bf(mb.y ? y.y : -1e30f);
          pk[6] = f2bf(mb.z ? y.z : -1e30f);
          pk[7] = f2bf(mb.w ? y.w : -1e30f);
        } else {
          pk[0] = f2bf(x.x); pk[1] = f2bf(x.y);
          pk[2] = f2bf(x.z); pk[3] = f2bf(x.w);
          pk[4] = f2bf(y.x); pk[5] = f2bf(y.y);
          pk[6] = f2bf(y.z); pk[7] = f2bf(y.w);
        }
        *(u16x8*)&((u16*)Cv)[grow + c0] = pk;
      }
    }
  }
}

// standalone GEMM kernel (QK with bias+mask; PV with f32 out)
template<bool HAS_BIAS, int MODE, bool HAS_MASK>
__global__ __launch_bounds__(256, 4) void gemm128(
    const u16* __restrict__ A, const u16* __restrict__ B,
    const float* __restrict__ bias, const int* __restrict__ mask,
    void* __restrict__ Cv,
    int M, int N, int K, long sA, long sB, long sC, long sMask, long sBias,
    float scale) {
  __shared__ SmemT sm;
  const int did = blockIdx.x + gridDim.x * (blockIdx.y + gridDim.y * blockIdx.z);
  gemm128_body<HAS_BIAS, MODE, HAS_MASK>(
      sm, threadIdx.x, A, B, bias, mask, Cv, M, N, K, sA, sB, sC, sMask,
      sBias, scale, did, gridDim.x, gridDim.y, gridDim.z);
}

// ---------------------------------------------------------------------------
// fused_prep (4352 blocks):
//  [0,4096):   input converts — blocks <2048 kv rows, else query rows
//  [4096,4224): merged weight GEMMs z=0: Mt=bt(WkT,WqT), z=1: Wvo=bt(wo,WvT)
//  [4224,4352): bgemv — <64: wvec = scale*WkT.bq ; >=64: bvo = wo.bv + bo
// ---------------------------------------------------------------------------
__global__ __launch_bounds__(256, 4) void fused_prep(
    const float* __restrict__ kv, const float* __restrict__ query,
    u16* __restrict__ kvbf, u16* __restrict__ qbf,
    const u16* __restrict__ WkT, const u16* __restrict__ WqT,
    u16* __restrict__ Mt, const u16* __restrict__ wo,
    const float* __restrict__ bq, const float* __restrict__ bv,
    const float* __restrict__ bo, float* __restrict__ wvec,
    float* __restrict__ bvo) {
  __shared__ SmemT sm;
  const int tid = threadIdx.x;
  const int bid = blockIdx.x;
  const int lane = tid & 63, wv_ = tid >> 6;
  if (bid < 4096) {
    const bool qside = bid >= 2048;
    const long blk = qside ? bid - 2048 : bid;
    const float* src_base = qside ? query : kv;
    u16* dst_base = qside ? qbf : kvbf;
#pragma unroll
    for (int r = 0; r < 2; ++r) {
      const long row = blk * 8 + wv_ * 2 + r;
      const float* src = &src_base[row * 1024 + lane * 16];
      const float4 a0 = *(const float4*)src;
      const float4 a1 = *(const float4*)(src + 4);
      const float4 a2 = *(const float4*)(src + 8);
      const float4 a3 = *(const float4*)(src + 12);
      u16x8 p0, p1;
      p0[0] = f2bf(a0.x); p0[1] = f2bf(a0.y); p0[2] = f2bf(a0.z); p0[3] = f2bf(a0.w);
      p0[4] = f2bf(a1.x); p0[5] = f2bf(a1.y); p0[6] = f2bf(a1.z); p0[7] = f2bf(a1.w);
      p1[0] = f2bf(a2.x); p1[1] = f2bf(a2.y); p1[2] = f2bf(a2.z); p1[3] = f2bf(a2.w);
      p1[4] = f2bf(a3.x); p1[5] = f2bf(a3.y); p1[6] = f2bf(a3.z); p1[7] = f2bf(a3.w);
      *(u16x8*)&dst_base[row * 1024 + lane * 16] = p0;
      *(u16x8*)&dst_base[row * 1024 + lane * 16 + 8] = p1;
    }
  } else if (bid < 4224) {
    gemm128_body<false, 0, false>(
        sm, tid, WkT, WqT, nullptr, nullptr, Mt, 1024, 1024, 1024,
        -2097152L, 2097152L, 1048576L, 0, 0, 1.f, bid - 4096, 8, 8, 2);
  } else {
    const int sub = bid - 4224;
    const bool second = sub >= 64;
    const u16* mat = second ? wo : WkT;
    const float* vec = second ? bv : bq;
    const int rb = (second ? sub - 64 : sub) * 16;
    float* w = sm.epi;
#pragma unroll
    for (int i = 0; i < 4; ++i) w[i * 256 + tid] = vec[i * 256 + tid];
    __syncthreads();
#pragma unroll
    for (int r = 0; r < 4; ++r) {
      const int row = rb + wv_ * 4 + r;
      const u16* p = &mat[(long)row * 1024 + lane * 16];
      const u16x8 a = *(const u16x8*)p;
      const u16x8 b = *(const u16x8*)(p + 8);
      float s = 0.f;
#pragma unroll
      for (int j = 0; j < 8; ++j) s += bf2f(a[j]) * w[lane * 16 + j];
#pragma unroll
      for (int j = 0; j < 8; ++j) s += bf2f(b[j]) * w[lane * 16 + 8 + j];
#pragma unroll
      for (int off = 32; off >= 1; off >>= 1) s += __shfl_xor(s, off);
      if (lane == 0) {
        if (second) bvo[row] = s + bo[row];
        else        wvec[row] = s * 0.03125f;
      }
    }
  }
}

// ---------------------------------------------------------------------------
// fused_mid (3072 blocks):
//  [0,1024):    qM  = bt(qbf, Mt)        (16384x1024x1024, grid 128x8x1)
//  [1024,2048): VwT = bt(Wvo, kv[b])     (1024x2048x1024 x8, grid 8x16x8)
//  [2048,3072): cgemv — cvec[row] = dot(kvbf[row,:], wvec)  (16 rows/block)
// ---------------------------------------------------------------------------
__global__ __launch_bounds__(256, 4) void fused_mid(
    const u16* __restrict__ qbf, const u16* __restrict__ Mt,
    u16* __restrict__ qM, const u16* __restrict__ Wvo,
    const u16* __restrict__ kvbf, u16* __restrict__ VwT,
    const float* __restrict__ wvec, float* __restrict__ cvec) {
  __shared__ SmemT sm;
  const int tid = threadIdx.x;
  const int bid = blockIdx.x;
  if (bid < 2048) {
    const bool isQM = bid < 1024;
    gemm128_body<false, 0, false>(
        sm, tid,
        isQM ? qbf : Wvo, isQM ? Mt : kvbf, nullptr, nullptr,
        isQM ? (void*)qM : (void*)VwT,
        isQM ? 16384 : 1024, isQM ? 1024 : 2048, 1024,
        0L, isQM ? 0L : 2097152L, isQM ? 0L : 2097152L, 0L, 0L, 1.f,
        isQM ? bid : bid - 1024,
        isQM ? 128 : 8, isQM ? 8 : 16, isQM ? 1 : 8);
  } else {
    const int lane = tid & 63, wv_ = tid >> 6;
    float* w = sm.epi;
#pragma unroll
    for (int i = 0; i < 4; ++i) w[i * 256 + tid] = wvec[i * 256 + tid];
    __syncthreads();
    const long rowbase = (long)(bid - 2048) * 16 + wv_ * 4;
#pragma unroll
    for (int r = 0; r < 4; ++r) {
      const long row = rowbase + r;
      const u16* p = &kvbf[row * 1024 + lane * 16];
      const u16x8 a = *(const u16x8*)p;
      const u16x8 b = *(const u16x8*)(p + 8);
      float s = 0.f;
#pragma unroll
      for (int j = 0; j < 8; ++j) s += bf2f(a[j]) * w[lane * 16 + j];
#pragma unroll
      for (int j = 0; j < 8; ++j) s += bf2f(b[j]) * w[lane * 16 + 8 + j];
#pragma unroll
      for (int off = 32; off >= 1; off >>= 1) s += __shfl_xor(s, off);
      if (lane == 0) cvec[row] = s;
    }
  }
}

// ---------------------------------------------------------------------------
// Algebraic fusions (torch Linear: x @ W.T + b; softmax over kv axis j):
//   S[q,j] = scale*(query.M)[q,:].kv[j,:] + c[j] (+ row-consts dropped),
//     M = Wq^T.Wk (as Mt = gemm_bt(WkT, WqT)), c[j] = scale*kv[j].(Wk^T bq)
//   out = P.Vw + bvo,  Vw^T = gemm_bt(Wvo, kv) (Wvo = Wo.Wv),
//   bvo = Wo.bv + bo   (valid since sum_j P = 1)
// ---------------------------------------------------------------------------
extern "C" void kernel_launch(void* const* d_in, const int* in_sizes, int n_in,
                              void* d_out, int out_size, void* d_ws, size_t ws_size,
                              hipStream_t stream) {
  const float* query = (const float*)d_in[0];   // [8,2048,1024]
  const float* kv    = (const float*)d_in[1];   // [8,2048,1024]
  const int*   mask  = (const int*)d_in[2];     // [8,2048,2048]
  const float* Wq = (const float*)d_in[3];
  const float* bq = (const float*)d_in[4];
  const float* Wk = (const float*)d_in[5];
  const float* bk = (const float*)d_in[6];      // unused: softmax-invariant
  const float* Wv = (const float*)d_in[7];
  const float* bv = (const float*)d_in[8];
  const float* Wo = (const float*)d_in[9];
  const float* bo = (const float*)d_in[10];
  float* out = (float*)d_out;
  (void)bk;

  char* ws = (char*)d_ws;
  const size_t MB = (size_t)1 << 20;
  u16* qbf  = (u16*)(ws + 0);          // 32MB query bf16
  u16* kvbf = (u16*)(ws + 32 * MB);    // 32MB kv bf16 (QK B-operand directly)
  u16* wo   = (u16*)(ws + 70 * MB);    // 2MB  Wo bf16 plain
  u16* WqT  = (u16*)(ws + 72 * MB);    // 2MB each: Wq^T, Wk^T, Wv^T
  u16* WkT  = (u16*)(ws + 74 * MB);
  u16* WvT  = (u16*)(ws + 76 * MB);
  u16* Mt   = (u16*)(ws + 78 * MB);    // 2MB  Mt = gemm_bt(WkT, WqT)
  u16* Wvo  = (u16*)(ws + 80 * MB);    // 2MB  Wo.Wv (Mt + 1048576 elems)
  float* wvec = (float*)(ws + 82 * MB);             // 4KB scale*Wk^T.bq
  float* bvo  = (float*)(ws + 82 * MB + 65536);     // 4KB Wo.bv+bo
  float* cvec = (float*)(ws + 83 * MB);             // 64KB c[8][2048]
  u16* qM   = (u16*)(ws + 84 * MB);    // 32MB query.M bf16
  u16* VwT  = (u16*)(ws + 116 * MB);   // 32MB [8][1024][2048]
  u16* S    = (u16*)(ws + 148 * MB);   // 64MB [8][2048][2048] bf16

  const long sQK = (long)2048 * 1024;
  const long sS  = (long)2048 * 2048;

  // 1) weight prep (transposed bf16 for Wq/Wk/Wv, plain for Wo)
  cvt_wt<<<dim3(16, 16, 4), 256, 0, stream>>>(Wq, Wk, Wv, Wo,
                                              WqT, WkT, WvT, wo);

  // 2) fused: input converts + merged weight GEMMs + bias GEMVs
  fused_prep<<<4352, 256, 0, stream>>>(kv, query, kvbf, qbf,
                                       WkT, WqT, Mt, wo, bq, bv, bo,
                                       wvec, bvo);

  // 3) fused: qM + VwT + cvec
  fused_mid<<<3072, 256, 0, stream>>>(qbf, Mt, qM, Wvo, kvbf, VwT,
                                      wvec, cvec);

  // 4) S = scale*(qM.kv^T) + c[b][j], masked (0 -> -1e30)
  gemm128<true, 0, true><<<dim3(16, 16, 8), 256, 0, stream>>>(
      qM, kvbf, cvec, mask, S, 2048, 2048, 1024, sQK, sQK, sS, sS, 2048,
      0.03125f);

  // 5) row softmax (in place on S)
  softmax_rows<<<16384, 256, 0, stream>>>(S);

  // 6) out = P.Vw + bvo   (fp32 direct to d_out, B = VwT)
  gemm128<true, 1, false><<<dim3(16, 8, 8), 256, 0, stream>>>(
      S, VwT, bvo, nullptr, out, 2048, 1024, 2048, sS, sQK, sQK, 0, 0, 1.f);
}